// Round 1
// baseline (70.025 us; speedup 1.0000x reference)
//
#include <hip/hip_runtime.h>

// Segment-mean of gathered embeddings.
// emb:  [N_ITEMS, 128] f32
// ids:  [TOTAL] int32 (gather indices)
// seg:  [TOTAL] int32, sorted ascending (session id per item)
// out:  [NSESS, 128] f32 = mean of emb[ids[j]] over j in session s (0 if empty)

constexpr int D = 128;

// Kernel 1: starts[s] = lower_bound(seg, s) for s in [0, nsess]
__global__ void find_starts_kernel(const int* __restrict__ seg, int total,
                                   int nsess, int* __restrict__ starts) {
    int s = blockIdx.x * blockDim.x + threadIdx.x;
    if (s > nsess) return;
    int lo = 0, hi = total;
    while (lo < hi) {
        int mid = (lo + hi) >> 1;
        if (seg[mid] < s) lo = mid + 1; else hi = mid;
    }
    starts[s] = lo;
}

// Kernel 2: one block (256 threads = 8 groups x 32 lanes) per session.
// Each group of 32 lanes reads one full 128-f32 row per iteration as float4
// (512 B coalesced); groups stride over the session's items; LDS reduce.
__global__ __launch_bounds__(256)
void seg_mean_kernel(const float* __restrict__ emb,
                     const int* __restrict__ ids,
                     const int* __restrict__ starts,
                     float* __restrict__ out) {
    const int s   = blockIdx.x;
    const int beg = starts[s];
    const int end = starts[s + 1];
    const int tid  = threadIdx.x;
    const int g    = tid >> 5;   // group 0..7
    const int lane = tid & 31;   // lane within group; covers dims lane*4..lane*4+3

    float4 acc = make_float4(0.f, 0.f, 0.f, 0.f);
    for (int j = beg + g; j < end; j += 8) {
        const int id = ids[j];
        const float4 v =
            reinterpret_cast<const float4*>(emb + (size_t)id * D)[lane];
        acc.x += v.x; acc.y += v.y; acc.z += v.z; acc.w += v.w;
    }

    __shared__ float4 red[256];
    red[tid] = acc;
    __syncthreads();

    if (tid < 32) {
        float4 sum = red[tid];
        #pragma unroll
        for (int gg = 1; gg < 8; ++gg) {
            const float4 v = red[gg * 32 + tid];
            sum.x += v.x; sum.y += v.y; sum.z += v.z; sum.w += v.w;
        }
        const int cnt = end - beg;
        const float inv = 1.0f / (float)(cnt > 0 ? cnt : 1);
        const float4 o = make_float4(sum.x * inv, sum.y * inv,
                                     sum.z * inv, sum.w * inv);
        reinterpret_cast<float4*>(out + (size_t)s * D)[tid] = o;
    }
}

extern "C" void kernel_launch(void* const* d_in, const int* in_sizes, int n_in,
                              void* d_out, int out_size, void* d_ws, size_t ws_size,
                              hipStream_t stream) {
    const float* emb = (const float*)d_in[0];
    const int*   ids = (const int*)d_in[1];
    const int*   seg = (const int*)d_in[2];
    float*       out = (float*)d_out;

    const int total = in_sizes[1];        // TOTAL_ITEMS
    const int nsess = out_size / D;       // N_SESSIONS

    int* starts = (int*)d_ws;             // (nsess + 1) ints

    {
        const int threads = 256;
        const int blocks = (nsess + 1 + threads - 1) / threads;
        find_starts_kernel<<<blocks, threads, 0, stream>>>(seg, total, nsess, starts);
    }
    seg_mean_kernel<<<nsess, 256, 0, stream>>>(emb, ids, starts, out);
}

// Round 2
// 67.818 us; speedup vs baseline: 1.0326x; 1.0326x over previous
//
#include <hip/hip_runtime.h>

// Segment-mean of gathered embeddings.
// emb:  [N_ITEMS, 128] f32
// ids:  [TOTAL] int32 (gather indices)
// seg:  [TOTAL] int32, sorted ascending (session id per item)
// out:  [NSESS, 128] f32 = mean of emb[ids[j]] over j in session s (0 if empty)

constexpr int D = 128;

// starts[s] = lower_bound(seg, s): diff-scan, one thread per item.
__global__ void find_starts_diff(const int* __restrict__ seg, int total,
                                 int nsess, int* __restrict__ starts) {
    int j = blockIdx.x * blockDim.x + threadIdx.x;
    if (j >= total) return;
    const int cur  = seg[j];
    const int prev = (j == 0) ? -1 : seg[j - 1];
    for (int s = prev + 1; s <= cur; ++s) starts[s] = j;   // covers starts[0]=0
    if (j == total - 1) {
        for (int s = cur + 1; s <= nsess; ++s) starts[s] = total;
    }
}

// One wave (64 lanes) per session: 2 groups of 32 lanes, each group reads one
// full 128-f32 row per step as float4 (512 B coalesced). 4-deep unroll keeps
// up to 8 row loads in flight per wave to hide random L2/L3-miss latency.
__global__ __launch_bounds__(256)
void seg_mean_kernel(const float* __restrict__ emb,
                     const int* __restrict__ ids,
                     const int* __restrict__ starts,
                     float* __restrict__ out, int nsess) {
    const int tid  = threadIdx.x;
    const int s    = blockIdx.x * 4 + (tid >> 6);   // one wave per session
    if (s >= nsess) return;
    const int lane = tid & 63;
    const int g    = lane >> 5;    // group 0/1: interleaved items (even/odd)
    const int l32  = lane & 31;    // covers dims l32*4 .. l32*4+3

    const int beg = starts[s];
    const int end = starts[s + 1];

    float4 acc = make_float4(0.f, 0.f, 0.f, 0.f);
    int j = beg + g;

    // main loop: 4 items per group per trip (stride 2 within the pair-split)
    for (; j + 6 < end; j += 8) {
        const int i0 = ids[j];
        const int i1 = ids[j + 2];
        const int i2 = ids[j + 4];
        const int i3 = ids[j + 6];
        const float4 v0 = reinterpret_cast<const float4*>(emb + (size_t)i0 * D)[l32];
        const float4 v1 = reinterpret_cast<const float4*>(emb + (size_t)i1 * D)[l32];
        const float4 v2 = reinterpret_cast<const float4*>(emb + (size_t)i2 * D)[l32];
        const float4 v3 = reinterpret_cast<const float4*>(emb + (size_t)i3 * D)[l32];
        acc.x += v0.x + v1.x + v2.x + v3.x;
        acc.y += v0.y + v1.y + v2.y + v3.y;
        acc.z += v0.z + v1.z + v2.z + v3.z;
        acc.w += v0.w + v1.w + v2.w + v3.w;
    }
    for (; j < end; j += 2) {
        const int id = ids[j];
        const float4 v = reinterpret_cast<const float4*>(emb + (size_t)id * D)[l32];
        acc.x += v.x; acc.y += v.y; acc.z += v.z; acc.w += v.w;
    }

    // combine the two 32-lane groups (lane i += lane i+32)
    acc.x += __shfl_down(acc.x, 32);
    acc.y += __shfl_down(acc.y, 32);
    acc.z += __shfl_down(acc.z, 32);
    acc.w += __shfl_down(acc.w, 32);

    if (lane < 32) {
        const int cnt = end - beg;
        const float inv = (cnt > 0) ? 1.0f / (float)cnt : 0.0f;  // empty -> 0
        const float4 o = make_float4(acc.x * inv, acc.y * inv,
                                     acc.z * inv, acc.w * inv);
        reinterpret_cast<float4*>(out + (size_t)s * D)[l32] = o;
    }
}

extern "C" void kernel_launch(void* const* d_in, const int* in_sizes, int n_in,
                              void* d_out, int out_size, void* d_ws, size_t ws_size,
                              hipStream_t stream) {
    const float* emb = (const float*)d_in[0];
    const int*   ids = (const int*)d_in[1];
    const int*   seg = (const int*)d_in[2];
    float*       out = (float*)d_out;

    const int total = in_sizes[1];        // TOTAL_ITEMS
    const int nsess = out_size / D;       // N_SESSIONS

    int* starts = (int*)d_ws;             // (nsess + 1) ints

    {
        const int threads = 256;
        const int blocks = (total + threads - 1) / threads;
        find_starts_diff<<<blocks, threads, 0, stream>>>(seg, total, nsess, starts);
    }
    {
        const int blocks = (nsess + 3) / 4;   // 4 sessions (waves) per block
        seg_mean_kernel<<<blocks, 256, 0, stream>>>(emb, ids, starts, out, nsess);
    }
}